// Round 6
// baseline (141.373 us; speedup 1.0000x reference)
//
#include <hip/hip_runtime.h>
#include <stddef.h>

#define NN 2048
#define DIN 128
#define HD 32

typedef __attribute__((ext_vector_type(8))) short short8;
typedef __attribute__((ext_vector_type(4))) float f32x4;
typedef __attribute__((ext_vector_type(4))) unsigned short us4;

constexpr float SLOPE = 0.2f;
constexpr float LC = 7.2134752044448170f; // log2(e)/TEMP

__device__ __forceinline__ unsigned int pack_rne(float a, float b){
    unsigned int xa = __float_as_uint(a), xb = __float_as_uint(b);
    unsigned int ra = (xa + 0x7fffu + ((xa >> 16) & 1u)) >> 16;
    unsigned int rb = (xb + 0x7fffu + ((xb >> 16) & 1u)) >> 16;
    return ra | (rb << 16);
}

__device__ __forceinline__ unsigned short bf16_rne(float a){
    unsigned int x = __float_as_uint(a);
    return (unsigned short)((x + 0x7fffu + ((x >> 16) & 1u)) >> 16);
}

// raw v_exp_f32: args here are <= 0 (max-subtracted); sub-denormal output
// differences are < 2^-126 and irrelevant at this tolerance.
__device__ __forceinline__ float fexp2(float x){
    float r; asm("v_exp_f32 %0, %1" : "=v"(r) : "v"(x)); return r;
}

// ---------------- kPrep: W -> Bt hi/lo bf16 [col=h*32+o][i]; mw -> bf16 ----
__global__ __launch_bounds__(256) void kPrep(const float* __restrict__ Wg,
                                             const float* __restrict__ mw,
                                             unsigned short* __restrict__ BtHi,
                                             unsigned short* __restrict__ BtLo,
                                             unsigned short* __restrict__ mwB)
{
    const int t = threadIdx.x;
    if (blockIdx.x < 16){
        const int col = blockIdx.x*8 + (t>>5);
        const int i0  = (t&31)*4;
        const int h = col >> 5, o = col & 31;
        us4 vh, vl;
        #pragma unroll
        for (int j = 0; j < 4; ++j){
            const float w = Wg[(h*DIN + i0 + j)*HD + o];
            const unsigned short hi = bf16_rne(w);
            const float hf = __uint_as_float((unsigned int)hi << 16);
            vh[j] = hi;
            vl[j] = bf16_rne(w - hf);
        }
        *(us4*)&BtHi[col*DIN + i0] = vh;
        *(us4*)&BtLo[col*DIN + i0] = vl;
    } else {
        const int col = (blockIdx.x - 16)*8 + (t>>5);
        const int k0  = (t&31)*4;
        const f32x4 v = *(const f32x4*)&mw[col*128 + k0];
        us4 p;
        #pragma unroll
        for (int j = 0; j < 4; ++j) p[j] = bf16_rne(v[j]);
        *(us4*)&mwB[col*128 + k0] = p;
    }
}

// ---------------- kWh: split-bf16 MFMA GEMM + fused score/WhT --------------
// (round-5 version minus the maxPartW epilogue)
__global__ __launch_bounds__(256) void kWh(const float* __restrict__ hg,
                                           const unsigned short* __restrict__ BtHi,
                                           const unsigned short* __restrict__ BtLo,
                                           const float* __restrict__ ag,
                                           unsigned short* __restrict__ WhT,
                                           float* __restrict__ sSrc,
                                           float* __restrict__ sDst)
{
    __shared__ float Hl[16][DIN+4];
    const int t = threadIdx.x;
    const int wv = t >> 6, lane = t & 63;
    const int q = lane >> 4, c = lane & 15;
    const int r0 = blockIdx.x * 16;
    const int b  = r0 >> 11;
    const int n0 = r0 & (NN-1);
    {
        const int r = t >> 5, c4 = t & 31;
        *(float4*)&Hl[r][c4*4] = *(const float4*)&hg[((size_t)b*NN + n0 + r)*DIN + c4*4];
        const int f2 = t + 256, r2 = f2 >> 5, c42 = f2 & 31;
        *(float4*)&Hl[r2][c42*4] = *(const float4*)&hg[((size_t)b*NN + n0 + r2)*DIN + c42*4];
    }
    __syncthreads();
    // A fragments hi/lo
    short8 Ahi[4], Alo[4];
    #pragma unroll
    for (int k = 0; k < 4; ++k){
        const float* sp = &Hl[c][k*32 + q*8];
        #pragma unroll
        for (int j2 = 0; j2 < 2; ++j2){
            const f32x4 x = *(const f32x4*)&sp[j2*4];
            #pragma unroll
            for (int j = 0; j < 4; ++j){
                const unsigned short hi = bf16_rne(x[j]);
                const float hf = __uint_as_float((unsigned int)hi << 16);
                ((unsigned short*)&Ahi[k])[j2*4+j] = hi;
                ((unsigned short*)&Alo[k])[j2*4+j] = bf16_rne(x[j] - hf);
            }
        }
    }
    const int hh = wv;
    const int bh = b*4 + hh;
    f32x4 acc0 = {0.f,0.f,0.f,0.f}, acc1 = {0.f,0.f,0.f,0.f};
    #pragma unroll
    for (int k = 0; k < 4; ++k){
        const int koff = k*32 + q*8;
        const short8 Bh0 = *(const short8*)&BtHi[(hh*32      + c)*DIN + koff];
        const short8 Bl0 = *(const short8*)&BtLo[(hh*32      + c)*DIN + koff];
        const short8 Bh1 = *(const short8*)&BtHi[(hh*32 + 16 + c)*DIN + koff];
        const short8 Bl1 = *(const short8*)&BtLo[(hh*32 + 16 + c)*DIN + koff];
        acc0 = __builtin_amdgcn_mfma_f32_16x16x32_bf16(Ahi[k], Bh0, acc0, 0, 0, 0);
        acc1 = __builtin_amdgcn_mfma_f32_16x16x32_bf16(Ahi[k], Bh1, acc1, 0, 0, 0);
        acc0 = __builtin_amdgcn_mfma_f32_16x16x32_bf16(Ahi[k], Bl0, acc0, 0, 0, 0);
        acc1 = __builtin_amdgcn_mfma_f32_16x16x32_bf16(Ahi[k], Bl1, acc1, 0, 0, 0);
        acc0 = __builtin_amdgcn_mfma_f32_16x16x32_bf16(Alo[k], Bh0, acc0, 0, 0, 0);
        acc1 = __builtin_amdgcn_mfma_f32_16x16x32_bf16(Alo[k], Bh1, acc1, 0, 0, 0);
    }
    // WhT[bh][o][n] bf16 (C/D layout: col=lane&15, row=q*4+reg)
    {
        us4 w0, w1;
        #pragma unroll
        for (int reg = 0; reg < 4; ++reg){
            w0[reg] = bf16_rne(acc0[reg]);
            w1[reg] = bf16_rne(acc1[reg]);
        }
        *(us4*)&WhT[((size_t)bh*32      + c)*NN + n0 + q*4] = w0;
        *(us4*)&WhT[((size_t)bh*32 + 16 + c)*NN + n0 + q*4] = w1;
    }
    const float aS0 = ag[hh*64 + c],      aS1 = ag[hh*64 + 16 + c];
    const float aD0 = ag[hh*64 + 32 + c], aD1 = ag[hh*64 + 48 + c];
    float vs[4], vd[4];
    #pragma unroll
    for (int reg = 0; reg < 4; ++reg){
        vs[reg] = acc0[reg]*aS0 + acc1[reg]*aS1;
        vd[reg] = acc0[reg]*aD0 + acc1[reg]*aD1;
    }
    #pragma unroll
    for (int m = 1; m <= 8; m <<= 1){
        #pragma unroll
        for (int reg = 0; reg < 4; ++reg){
            vs[reg] += __shfl_xor(vs[reg], m);
            vd[reg] += __shfl_xor(vd[reg], m);
        }
    }
    if (c == 0){
        *(f32x4*)&sSrc[(size_t)bh*NN + n0 + q*4] = (f32x4){vs[0],vs[1],vs[2],vs[3]};
        *(f32x4*)&sDst[(size_t)bh*NN + n0 + q*4] = (f32x4){vd[0],vd[1],vd[2],vd[3]};
    }
}

// ---------------- kAttnM: softmax + PV, m-halves split across wave pairs ----
// Max now computed in-block from sdl (exact bound over the actual u operands):
// 8 coalesced ds_read_b128 per lane + butterfly — no maxPartW, no extra barrier.
__global__ __launch_bounds__(256) void kAttnM(const unsigned short* __restrict__ WhT,
                                              const float* __restrict__ sSrc,
                                              const float* __restrict__ sDst,
                                              float* __restrict__ invZ,
                                              unsigned short* __restrict__ hcb)
{
    __shared__ float sdl[NN];            // LC * s_dst for the whole bh (8 KB)
    __shared__ float red[2][64][9];      // stride 9 (odd): 2 lanes/bank = free
    const int t = threadIdx.x;
    const int lane = t & 63;
    const int wv = t >> 6;
    const int q = lane >> 4, c = lane & 15;
    const int bh = blockIdx.x >> 6;
    const int tile = blockIdx.x & 63;
    const int rg = wv >> 1, mh = wv & 1;
    const int n0 = tile*32 + rg*16;
    const int b = bh >> 2, hh = bh & 3;
    for (int i = t; i < NN; i += 256) sdl[i] = LC * sDst[bh*NN + i];
    const float ssrc = sSrc[bh*NN + n0 + c];
    __syncthreads();
    // MX = max over sdl[0..2047] (LC-domain), redundantly per wave
    float MX = -1e30f;
    #pragma unroll
    for (int k = 0; k < 8; ++k){
        const f32x4 v4 = *(const f32x4*)&sdl[(lane<<2) + (k<<8)];
        MX = fmaxf(MX, fmaxf(fmaxf(v4[0], v4[1]), fmaxf(v4[2], v4[3])));
    }
    #pragma unroll
    for (int off = 32; off; off >>= 1) MX = fmaxf(MX, __shfl_xor(MX, off));
    const float Q0 = ssrc*LC + MX;
    const float R = fmaxf(Q0, SLOPE*Q0);
    const float a1 = ssrc*LC - R;
    const float a2 = SLOPE*LC*ssrc - R;
    const unsigned short* wb0 = WhT + (size_t)bh*32*NN + (size_t)c*NN + mh*1024 + q*8;
    const unsigned short* wb1 = wb0 + (size_t)16*NN;
    const float* sdb = &sdl[mh*1024];
    f32x4 acc0 = {0.f,0.f,0.f,0.f}, acc1 = {0.f,0.f,0.f,0.f};
    float Zp = 0.f;
    short8 bF0 = *(const short8*)&wb0[0];
    short8 bF1 = *(const short8*)&wb1[0];
    #pragma unroll 4
    for (int it = 0; it < 32; ++it){
        const int m8 = it*32 + q*8;
        const int nx = ((it+1) & 31)*32;       // wraps to 0 on last iter (harmless)
        const short8 nF0 = *(const short8*)&wb0[nx];
        const short8 nF1 = *(const short8*)&wb1[nx];
        const f32x4 u0 = *(const f32x4*)&sdb[m8];
        const f32x4 u1 = *(const f32x4*)&sdb[m8+4];
        float p[8];
        #pragma unroll
        for (int j = 0; j < 4; ++j){
            p[j]   = fexp2(fmaxf(a1 + u0[j], fmaf(SLOPE, u0[j], a2)));
            p[4+j] = fexp2(fmaxf(a1 + u1[j], fmaf(SLOPE, u1[j], a2)));
        }
        short8 aF;
        #pragma unroll
        for (int j = 0; j < 8; j += 2){
            ((unsigned int*)&aF)[j>>1] = (__float_as_uint(p[j]) >> 16)
                                       | (__float_as_uint(p[j+1]) & 0xffff0000u);
            Zp += p[j] + p[j+1];
        }
        acc0 = __builtin_amdgcn_mfma_f32_16x16x32_bf16(aF, bF0, acc0, 0, 0, 0);
        acc1 = __builtin_amdgcn_mfma_f32_16x16x32_bf16(aF, bF1, acc1, 0, 0, 0);
        bF0 = nF0; bF1 = nF1;
    }
    // per-wave: combine q-slices -> half-m Z per lane's row c
    Zp += __shfl_xor(Zp, 16);
    Zp += __shfl_xor(Zp, 32);
    // pair-reduce across m-halves through LDS
    if (mh == 1){
        #pragma unroll
        for (int k2 = 0; k2 < 4; ++k2){
            red[rg][lane][k2]     = acc0[k2];
            red[rg][lane][4 + k2] = acc1[k2];
        }
        red[rg][lane][8] = Zp;
    }
    __syncthreads();
    if (mh == 0){
        #pragma unroll
        for (int k2 = 0; k2 < 4; ++k2){
            acc0[k2] += red[rg][lane][k2];
            acc1[k2] += red[rg][lane][4 + k2];
        }
        Zp += red[rg][lane][8];
        const float iz = 1.0f / Zp;          // Z for row n0 + c
        if (q == 0) invZ[bh*NN + n0 + c] = iz;
        #pragma unroll
        for (int reg = 0; reg < 4; ++reg){
            const int row = q*4 + reg;
            const float izr = __shfl(iz, row);
            const size_t base = ((size_t)b*NN + n0 + row)*128 + hh*32;
            hcb[base + c]      = (unsigned short)((pack_rne(acc0[reg]*izr, 0.f)) & 0xffffu);
            hcb[base + 16 + c] = (unsigned short)((pack_rne(acc1[reg]*izr, 0.f)) & 0xffffu);
        }
    }
}

// ---------------- kTail: merge (blocks 0..255) || alpha (blocks 256..2303) --
__global__ __launch_bounds__(256) void kTail(const float* __restrict__ sSrc,
                                             const float* __restrict__ sDst,
                                             const float* __restrict__ invZ,
                                             const unsigned short* __restrict__ hcb,
                                             const unsigned short* __restrict__ mwB,
                                             const float* __restrict__ mbv,
                                             float* __restrict__ out0,
                                             float* __restrict__ out1)
{
    __shared__ float sdl[4][NN];     // alpha only (32 KB)
    __shared__ float mxl[4];
    const int t = threadIdx.x;
    const int wv = t >> 6, lane = t & 63;
    if (blockIdx.x < 256){
        // ---- merge: out0 = hcb(bf16) @ mwB^T + bias via MFMA ----
        const int q = lane >> 4, c = lane & 15;
        const int r0 = blockIdx.x*32 + (wv&1)*16;
        const int ch = (wv>>1)*64;
        f32x4 acc[4];
        #pragma unroll
        for (int ot = 0; ot < 4; ++ot) acc[ot] = (f32x4){0.f,0.f,0.f,0.f};
        #pragma unroll
        for (int ks = 0; ks < 4; ++ks){
            const short8 aF = *(const short8*)&hcb[((size_t)r0 + c)*128 + ks*32 + q*8];
            #pragma unroll
            for (int ot = 0; ot < 4; ++ot){
                const short8 bF = *(const short8*)&mwB[(size_t)(ch + ot*16 + c)*128 + ks*32 + q*8];
                acc[ot] = __builtin_amdgcn_mfma_f32_16x16x32_bf16(aF, bF, acc[ot], 0, 0, 0);
            }
        }
        #pragma unroll
        for (int ot = 0; ot < 4; ++ot){
            const int col = ch + ot*16 + c;
            const float bias = mbv[col];
            #pragma unroll
            for (int reg = 0; reg < 4; ++reg){
                const size_t row = (size_t)r0 + q*4 + reg;
                out0[row*128 + col] = acc[ot][reg] + bias;
            }
        }
        return;
    }
    // ---- alpha: out1[b][n][m] = 0.25 * sum_h alpha_h ----
    const int bidA = blockIdx.x - 256;
    const int b = bidA >> 9;
    const int n0 = (bidA & 511) * 4;
    for (int i = t; i < 4*NN; i += 256)
        sdl[i >> 11][i & (NN-1)] = LC * sDst[(size_t)(b*4 + (i>>11))*NN + (i & (NN-1))];
    __syncthreads();
    {   // wave w reduces head w's max from the staged sdl (LC-domain)
        float v = -1e30f;
        #pragma unroll
        for (int k = 0; k < 8; ++k){
            const f32x4 x = *(const f32x4*)&sdl[wv][(lane<<2) + (k<<8)];
            v = fmaxf(v, fmaxf(fmaxf(x[0], x[1]), fmaxf(x[2], x[3])));
        }
        #pragma unroll
        for (int off = 32; off; off >>= 1) v = fmaxf(v, __shfl_xor(v, off));
        if (lane == 0) mxl[wv] = v;
    }
    __syncthreads();
    float a1[4][4], a2[4][4], cf[4][4];   // [row][head]
    #pragma unroll
    for (int hh = 0; hh < 4; ++hh){
        const float MX = mxl[hh];
        #pragma unroll
        for (int rr = 0; rr < 4; ++rr){
            const int bhn = (b*4+hh)*NN + n0 + rr;
            const float ss = sSrc[bhn];
            const float Q0 = ss*LC + MX;
            const float R = fmaxf(Q0, SLOPE*Q0);
            a1[rr][hh] = ss*LC - R;
            a2[rr][hh] = SLOPE*LC*ss - R;
            cf[rr][hh] = 0.25f * invZ[bhn];
        }
    }
    #pragma unroll
    for (int half = 0; half < 2; ++half){
        const int m0 = half*1024 + t*4;
        const f32x4 u0 = *(const f32x4*)&sdl[0][m0];
        const f32x4 u1 = *(const f32x4*)&sdl[1][m0];
        const f32x4 u2 = *(const f32x4*)&sdl[2][m0];
        const f32x4 u3 = *(const f32x4*)&sdl[3][m0];
        #pragma unroll
        for (int rr = 0; rr < 4; ++rr){
            f32x4 v;
            #pragma unroll
            for (int e = 0; e < 4; ++e){
                float s;
                s  = cf[rr][0]*fexp2(fmaxf(a1[rr][0]+u0[e], fmaf(SLOPE, u0[e], a2[rr][0])));
                s += cf[rr][1]*fexp2(fmaxf(a1[rr][1]+u1[e], fmaf(SLOPE, u1[e], a2[rr][1])));
                s += cf[rr][2]*fexp2(fmaxf(a1[rr][2]+u2[e], fmaf(SLOPE, u2[e], a2[rr][2])));
                s += cf[rr][3]*fexp2(fmaxf(a1[rr][3]+u3[e], fmaf(SLOPE, u3[e], a2[rr][3])));
                v[e] = s;
            }
            __builtin_nontemporal_store(v, (f32x4*)&out1[((size_t)b*NN + n0 + rr)*NN + m0]);
        }
    }
}

extern "C" void kernel_launch(void* const* d_in, const int* in_sizes, int n_in,
                              void* d_out, int out_size, void* d_ws, size_t ws_size,
                              hipStream_t stream)
{
    const float* hg  = (const float*)d_in[0];
    const float* Wg  = (const float*)d_in[1];
    const float* ag  = (const float*)d_in[2];
    const float* mw  = (const float*)d_in[3];
    const float* mbv = (const float*)d_in[4];
    float* out0 = (float*)d_out;
    float* out1 = out0 + (size_t)4*NN*128;

    float* ws      = (float*)d_ws;
    float* sSrc    = ws;                       //    32,768 f32
    float* sDst    = sSrc + 32768;             //    32,768
    float* invZ    = sDst + 32768;             //    32,768
    unsigned short* hcb  = (unsigned short*)(invZ + 32768);   // 1,048,576 bf16
    unsigned short* WhT  = hcb + 1048576;      // 1,048,576 bf16 [bh][32][2048]
    unsigned short* BtHi = WhT + 1048576;      //    16,384 bf16
    unsigned short* BtLo = BtHi + 16384;       //    16,384
    unsigned short* mwB  = BtLo + 16384;       //    16,384

    hipLaunchKernelGGL(kPrep,  dim3(32),   dim3(256), 0, stream, Wg, mw, BtHi, BtLo, mwB);
    hipLaunchKernelGGL(kWh,    dim3(512),  dim3(256), 0, stream, hg, BtHi, BtLo, ag, WhT, sSrc, sDst);
    hipLaunchKernelGGL(kAttnM, dim3(1024), dim3(256), 0, stream, WhT, sSrc, sDst, invZ, hcb);
    hipLaunchKernelGGL(kTail,  dim3(2304), dim3(256), 0, stream, sSrc, sDst, invZ, hcb, mwB, mbv, out0, out1);
}